// Round 7
// baseline (251.791 us; speedup 1.0000x reference)
//
#include <hip/hip_runtime.h>

#define DD 256
#define BB 512
#define NL 2048            // e-quantization LUT entries

#define OFF_HFC 0          // 4 floats at start of d_ws

typedef float v2f __attribute__((ext_vector_type(2)));

__device__ __forceinline__ v2f mk2(float a, float b) { v2f r; r.x = a; r.y = b; return r; }

__device__ __forceinline__ v2f fma2(v2f a, v2f b, v2f c) {
#if __has_builtin(__builtin_elementwise_fma)
  return __builtin_elementwise_fma(a, b, c);   // -> v_pk_fma_f32
#else
  return mk2(fmaf(a.x, b.x, c.x), fmaf(a.y, b.y, c.y));
#endif
}

__device__ __forceinline__ float wave_red(float v) {
#pragma unroll
  for (int off = 32; off > 0; off >>= 1) v += __shfl_down(v, off, 64);
  return v;
}

// ---- fused: x row/col sums (LDS) + PWL table build + conv + fc1 accumulation ----
__global__ __launch_bounds__(1024, 8) void fused_kernel(
    const float* __restrict__ x,
    const float* __restrict__ w1, const float* __restrict__ b1,
    const float* __restrict__ w2, const float* __restrict__ b2p,
    const float* __restrict__ fc1w, float* __restrict__ ws) {
  const int b = blockIdx.x;          // 512 blocks = 1 per image
  const int tid = threadIdx.x;
  const int w = tid >> 6;            // wave 0..15
  const int lane = tid & 63;

  __shared__ float rowp[DD][17];     // 16 row partials per row (lanes 0..15)
  __shared__ float csl[16][DD];      // per-wave column partials
  __shared__ float rs_s[DD];
  __shared__ float cs_s[DD];
  __shared__ __align__(16) float tabP[264];
  __shared__ __align__(16) float wkA[DD][4];
  __shared__ unsigned short lut_s[NL];
  __shared__ float segsum_s[4][4];
  __shared__ float red_s[64];

  // ---- uniform PWL params (registers; short live range for w1/b1) ----
  float bp[10];
  {
#pragma unroll
    for (int c = 0; c < 10; ++c) bp[c] = -b1[c] / w1[c];
  }
  float lo = bp[0], hi = bp[0];
#pragma unroll
  for (int c = 1; c < 10; ++c) { lo = fminf(lo, bp[c]); hi = fmaxf(hi, bp[c]); }
  const float inv_step = (float)(NL - 3) / (hi - lo);
  const float bias = 1.0f - lo * inv_step;
  const float step = (hi - lo) / (float)(NL - 3);

  // ---- phase A: stream this image's 256 KB; row/col partials into LDS ----
  {
    float4 cacc = make_float4(0.f, 0.f, 0.f, 0.f);
    const float4* px = (const float4*)(x + ((size_t)b << 16) + ((size_t)(w * 16) << 8));
#pragma unroll
    for (int r = 0; r < 16; ++r) {
      float4 val = px[r * 64 + lane];
      cacc.x += val.x; cacc.y += val.y; cacc.z += val.z; cacc.w += val.w;
      float s = (val.x + val.y) + (val.z + val.w);
      s += __shfl_xor(s, 32, 64);
      s += __shfl_xor(s, 16, 64);
      if (lane < 16) rowp[w * 16 + r][lane] = s;   // lanes {l,l+16,l+32,l+48} summed
    }
    ((float4*)csl[w])[lane] = cacc;
  }

  // ---- overlapped with load latency: wk loads + LUT + coefficient table ----
  if (tid < 256) {
#pragma unroll
    for (int k = 0; k < 4; ++k) wkA[tid][k] = fc1w[k * (BB * DD) + b * DD + tid];
  }
  {                                  // LUT: 2 entries/thread, one packed u32 write
    unsigned int pack = 0;
#pragma unroll
    for (int h = 0; h < 2; ++h) {
      const int k = tid * 2 + h;
      const float xx = lo + (float)(k - 1) * step;   // cell k left edge
      int s = 0;
#pragma unroll
      for (int c = 0; c < 10; ++c) s += (bp[c] < xx) ? 1 : 0;
      pack |= ((unsigned int)(s * 96)) << (16 * h);
    }
    ((unsigned int*)lut_s)[tid] = pack;
  }
  if (tid < 99) {                    // coefficient table cell per thread
    int rank[10];
#pragma unroll
    for (int c = 0; c < 10; ++c) {
      int r = 0;
#pragma unroll
      for (int k = 0; k < 10; ++k)
        r += (bp[k] < bp[c] || (bp[k] == bp[c] && k < c)) ? 1 : 0;
      rank[c] = r;
    }
    const int s = tid / 9, tt = tid % 9;   // tt = dr*3 + kc
    const int dr = tt / 3, kc = tt % 3;
    float A = 0.f, Bv = 0.f;
    for (int c = 0; c < 10; ++c) {
      const float w1c = w1[c], b1c = b1[c];
      bool act = (w1c > 0.f) ? (rank[c] < s)
               : ((w1c < 0.f) ? (rank[c] >= s) : (b1c > 0.f));
      if (act) { A += w1c * w2[c * 9 + tt]; Bv += b1c * w2[c * 9 + tt]; }
    }
    const int base = (s * 3 + kc) * 8;     // layout: A0,A1,B0,B1,A2,B2,_,_
    tabP[base + ((dr == 2) ? 4 : dr)]       = A;
    tabP[base + ((dr == 2) ? 5 : (2 + dr))] = Bv;
  }
  __syncthreads();

  // ---- finalize rs / cs / segment wk sums ----
  if (tid < 256) {
    const float* rp = rowp[tid];
    float s = 0.f;
#pragma unroll
    for (int k = 0; k < 16; ++k) s += rp[k];
    rs_s[tid] = s;
  } else if (tid < 512) {
    const int c = tid - 256;
    float s = 0.f;
#pragma unroll
    for (int wv = 0; wv < 16; ++wv) s += csl[wv][c];
    cs_s[c] = s;
  } else if (tid < 528) {
    const int ss = (tid - 512) >> 2, k = (tid - 512) & 3;
    float s = 0.f;
#pragma unroll
    for (int r = 0; r < 64; ++r) s += wkA[ss * 64 + r][k];
    segsum_s[ss][k] = s;
  }
  __syncthreads();

  // ---- phase B: conv + relu + direct fc1 accumulation ----
  const int seg = w >> 2;            // row segment
  const int wb = (w - seg) & 3;      // column band (anti-diagonal balance)
  const int j = wb * 64 + lane;
  const int jmin = wb * 64;
  const int r0 = seg * 64, r1 = r0 + 64;

  const float b2v = b2p[0];
  const float yb = fmaxf(b2v, 0.f);
  const float fxmax = (float)(NL - 1);

  float csr[3], vf[3];
  csr[0] = (j >= 1) ? cs_s[j - 1] : 0.f;
  csr[1] = cs_s[j];
  csr[2] = (j < DD - 1) ? cs_s[j + 1] : 0.f;
  vf[0] = (j >= 1) ? 1.f : 0.f;
  vf[1] = 1.f;
  vf[2] = (j < DD - 1) ? 1.f : 0.f;
  v2f vf2[3];
#pragma unroll
  for (int kc = 0; kc < 3; ++kc) vf2[kc] = mk2(vf[kc], vf[kc]);

  const int nt = min(max(jmin - 2 - r0, 0), 64);   // wave-trivial output rows
  const int rfirst = r0 + nt;
  const int iend = (r1 == DD) ? DD - 1 : r1;

  float P = 0.f, Q = 0.f;
  float vcol = 64.f * yb;                          // closed-form yb contribution
  v2f a01 = mk2(yb * segsum_s[seg][0], yb * segsum_s[seg][1]);
  v2f a23 = mk2(yb * segsum_s[seg][2], yb * segsum_s[seg][3]);

#define TAP_CORE(KC, E, M2, MS)                                              \
  {                                                                          \
    float fx = fmaf((E), inv_step, bias);                                    \
    fx = fminf(fmaxf(fx, 0.f), fxmax);                                       \
    const int off = (int)lut_s[(int)fx];                                     \
    const char* tp = (const char*)tabP + (off + (KC) * 32);                  \
    const float4 ab = *(const float4*)tp;         /* A0,A1,B0,B1 */          \
    const float2 ab2 = *(const float2*)(tp + 16); /* A2,B2 */                \
    v2f tv = fma2(mk2(ab.x, ab.y), mk2((E), (E)), mk2(ab.z, ab.w));          \
    R01 = fma2((M2), tv, R01);                                               \
    R2 = fmaf((MS), fmaf(ab2.x, (E), ab2.y), R2);                            \
  }

  if (rfirst < r1) {
    if (seg > wb) {
      for (int i = r0 - 1; i <= r0; ++i) {   // 2 guarded warmup iters
        const float rsv = rs_s[i];
        v2f R01 = mk2(0.f, 0.f); float R2 = 0.f;
#pragma unroll
        for (int kc = 0; kc < 3; ++kc) {
          const float e = rsv + csr[kc];
          const float m = ((j - 1 + kc) <= i) ? vf[kc] : 0.f;
          TAP_CORE(kc, e, mk2(m, m), m)
        }
        P = Q + R01.y; Q = R01.x;
      }
      for (int i = r0 + 1; i <= iend; ++i) { // interior: all lanes in-tril
        const float rsv = rs_s[i];
        v2f R01 = mk2(0.f, 0.f); float R2 = 0.f;
#pragma unroll
        for (int kc = 0; kc < 3; ++kc) {
          const float e = rsv + csr[kc];
          TAP_CORE(kc, e, vf2[kc], vf[kc])
        }
        const float yd = fmaxf(P + R2 + b2v, 0.f) - yb;
        vcol += yd;
        const float4 wkv = *(const float4*)wkA[i - 1];
        a01 = fma2(mk2(yd, yd), mk2(wkv.x, wkv.y), a01);
        a23 = fma2(mk2(yd, yd), mk2(wkv.z, wkv.w), a23);
        P = Q + R01.y; Q = R01.x;
      }
    } else {
      const int ibeg = (nt > 0) ? rfirst - 1 : ((r0 == 0) ? 0 : r0 - 1);
      const int ffrom = rfirst + 1;
      for (int i = ibeg; i <= iend; ++i) {   // guarded (diagonal) loop
        const float rsv = rs_s[i];
        v2f R01 = mk2(0.f, 0.f); float R2 = 0.f;
        if (j - 1 <= i) {
#pragma unroll
          for (int kc = 0; kc < 3; ++kc) {
            const float e = rsv + csr[kc];
            const float m = ((j - 1 + kc) <= i) ? vf[kc] : 0.f;
            TAP_CORE(kc, e, mk2(m, m), m)
          }
        }
        if (i >= ffrom) {
          const float yd = fmaxf(P + R2 + b2v, 0.f) - yb;
          vcol += yd;
          const float4 wkv = *(const float4*)wkA[i - 1];
          a01 = fma2(mk2(yd, yd), mk2(wkv.x, wkv.y), a01);
          a23 = fma2(mk2(yd, yd), mk2(wkv.z, wkv.w), a23);
        }
        P = Q + R01.y; Q = R01.x;
      }
    }
  }
  if (r1 == DD) {                    // flush output row 255
    const float yd = fmaxf(P + b2v, 0.f) - yb;
    vcol += yd;
    const float4 wkv = *(const float4*)wkA[DD - 1];
    a01 = fma2(mk2(yd, yd), mk2(wkv.x, wkv.y), a01);
    a23 = fma2(mk2(yd, yd), mk2(wkv.z, wkv.w), a23);
  }

  // column-sum term: vcol * Wk[b, j]
  const float4 wkj = *(const float4*)wkA[j];
  a01 = fma2(mk2(vcol, vcol), mk2(wkj.x, wkj.y), a01);
  a23 = fma2(mk2(vcol, vcol), mk2(wkj.z, wkj.w), a23);

  float acc0 = wave_red(a01.x), acc1 = wave_red(a01.y);
  float acc2 = wave_red(a23.x), acc3 = wave_red(a23.y);
  if (lane == 0) {
    red_s[w * 4 + 0] = acc0; red_s[w * 4 + 1] = acc1;
    red_s[w * 4 + 2] = acc2; red_s[w * 4 + 3] = acc3;
  }
  __syncthreads();
  if (tid < 4) {
    float s = 0.f;
#pragma unroll
    for (int wv = 0; wv < 16; ++wv) s += red_s[wv * 4 + tid];
    atomicAdd(&ws[OFF_HFC + tid], s);
  }
#undef TAP_CORE
}

// ---- K3: relu(fc1) -> fc2 -> 2 outputs ----
__global__ void fc_kernel(const float* __restrict__ fc1b, const float* __restrict__ fc2w,
                          const float* __restrict__ fc2b, const float* __restrict__ ws,
                          float* __restrict__ out) {
  if (threadIdx.x == 0 && blockIdx.x == 0) {
    float o0 = fc2b[0], o1 = fc2b[1];
#pragma unroll
    for (int k = 0; k < 4; ++k) {
      float h = fmaxf(ws[OFF_HFC + k] + fc1b[k], 0.f);
      o0 += fc2w[k] * h;
      o1 += fc2w[4 + k] * h;
    }
    out[0] = o0; out[1] = o1;
  }
}

extern "C" void kernel_launch(void* const* d_in, const int* in_sizes, int n_in,
                              void* d_out, int out_size, void* d_ws, size_t ws_size,
                              hipStream_t stream) {
  const float* x    = (const float*)d_in[0];
  const float* w1   = (const float*)d_in[1];
  const float* b1   = (const float*)d_in[2];
  const float* w2   = (const float*)d_in[3];
  const float* b2   = (const float*)d_in[4];
  const float* fc1w = (const float*)d_in[5];
  const float* fc1b = (const float*)d_in[6];
  const float* fc2w = (const float*)d_in[7];
  const float* fc2b = (const float*)d_in[8];
  float* out = (float*)d_out;
  float* ws  = (float*)d_ws;

  hipMemsetAsync(ws + OFF_HFC, 0, 4 * sizeof(float), stream);  // zero fc1 accumulators
  hipLaunchKernelGGL(fused_kernel, dim3(512), dim3(1024), 0, stream,
                     x, w1, b1, w2, b2, fc1w, ws);
  hipLaunchKernelGGL(fc_kernel, dim3(1), dim3(64), 0, stream, fc1b, fc2w, fc2b, ws, out);
}